// Round 21
// baseline (303.391 us; speedup 1.0000x reference)
//
#include <hip/hip_runtime.h>
#include <hip/hip_bf16.h>
#include <stdint.h>

// ---------------------------------------------------------------------------
// B=256 D=28 N=23 F=128 O=64 H=128 Y=7.  NBSEQ=5888 = 184 blocks x 32 seqs.
// R21 (kernB + new kernM; kernA/prep = R20 known-good):
//  - kernM: zmean[blk][288] = mean over d of zlin-hi (bit-identical to the
//    old in-kernB x2 accumulation).  Decoder steps stage zmean via the normal
//    staging path -> X2 LDS region, per-step x2 adds, and the step-27
//    two-barrier special case all deleted from kernB.  LDS 92->83KB.
//  - kernB: L1 kt=0 weight A-frags prefetched BEFORE the barrier (the only
//    loads the barrier fence was serializing); L1 loop peeled kt=0.
// ---------------------------------------------------------------------------

#define DB 256
#define DD 28
#define DN 23
#define DF 128
#define DO 64
#define DH 128
#define DY 7
#define NBSEQ (DN*DB)
#define ADJSZ (DB*DD*DN*DN)
#define GBLK 184
#define L2E 1.4426950408889634f

// workspace byte offsets
#define WB0_OFF   47480832u            // zlin = 7168*414*16
#define WB1_OFF   47710208u
#define WPK_OFF   47972352u
#define GPK_OFF   48103424u
#define ZME_OFF   48119808u            // zmean: 184*288*16 = 847872

using v8bf  = __attribute__((ext_vector_type(8))) __bf16;
using f32x4 = __attribute__((ext_vector_type(4))) float;
using u32x4 = __attribute__((ext_vector_type(4))) unsigned int;
using u16x4 = __attribute__((ext_vector_type(4))) unsigned short;

__device__ __forceinline__ float fsig(float x)  { return 1.f/(1.f+__expf(-x)); }
__device__ __forceinline__ float ftanh(float x) { return 1.f - 2.f/(__expf(2.f*x)+1.f); }
__device__ __forceinline__ float fsigR(float x){
    return __builtin_amdgcn_rcpf(1.f + __builtin_amdgcn_exp2f(-x*L2E));
}
__device__ __forceinline__ float ftanhR(float x){
    return 1.f - 2.f*__builtin_amdgcn_rcpf(__builtin_amdgcn_exp2f(x*(2.f*L2E))+1.f);
}
__device__ __forceinline__ float fsig2(float a){
    return __builtin_amdgcn_rcpf(1.f + __builtin_amdgcn_exp2f(-a));
}
__device__ __forceinline__ float ftanh2(float a){
    return 1.f - 2.f*__builtin_amdgcn_rcpf(__builtin_amdgcn_exp2f(a)+1.f);
}
__device__ __forceinline__ float ftanhc(float c){
    return 1.f - 2.f*__builtin_amdgcn_rcpf(__builtin_amdgcn_exp2f(c*(2.f*L2E))+1.f);
}

__device__ __forceinline__ unsigned short f2bf(float f){
    unsigned u = __builtin_bit_cast(unsigned, f);
    return (unsigned short)((u + 0x7FFFu + ((u>>16)&1u)) >> 16);
}
__device__ __forceinline__ float bf2f(unsigned short b){
    return __builtin_bit_cast(float, (unsigned)b << 16);
}
__device__ __forceinline__ uint4 ntload4(const uint4* p){
    u32x4 v = __builtin_nontemporal_load((const u32x4*)p);
    return *(uint4*)&v;
}
__device__ __forceinline__ unsigned pkbf(float lo, float hi){
    unsigned r;
    asm("v_cvt_pk_bf16_f32 %0, %1, %2" : "=v"(r) : "v"(lo), "v"(hi));
    return r;
}

#define MFMA_(acc_, A_, B_) acc_ = __builtin_amdgcn_mfma_f32_16x16x32_bf16(A_, B_, acc_, 0, 0, 0)

// ---------------------------------------------------------------------------
// Prep (R17/R18: LSTM rows prescaled; g-gate by 2*log2e, others log2e)
// ---------------------------------------------------------------------------
__global__ __launch_bounds__(256) void kernPrep(
    const float* __restrict__ wih0, const float* __restrict__ whh0,
    const float* __restrict__ wih1, const float* __restrict__ whh1,
    const float* __restrict__ glw1, const float* __restrict__ glw2,
    const float* __restrict__ gcn_w,
    unsigned short* __restrict__ wb0, unsigned short* __restrict__ wb1,
    unsigned short* __restrict__ wpk, unsigned short* __restrict__ gpk)
{
    int idx = blockIdx.x*256 + threadIdx.x;
    if (idx < 114688){
        int e = idx&7, l = (idx>>3)&63, mt = (idx>>9)&31, kt = idx>>14;
        int rit = l&15, lj = rit>>2, g = rit&3;
        int r = g*128 + (mt>>2)*16 + lj*4 + (mt&3);
        int k = kt*32 + (l>>4)*8 + e;
        float v = 0.f;
        if (k < 65)                  v = wih0[r*65 + k];
        else if (k >= 72 && k < 200) v = whh0[r*128 + (k-72)];
        v *= (g==2) ? (2.f*L2E) : L2E;
        wb0[idx] = f2bf(v);
        return;
    }
    idx -= 114688;
    if (idx < 131072){
        int e = idx&7, l = (idx>>3)&63, mt = (idx>>9)&31, kt = idx>>14;
        int rit = l&15, lj = rit>>2, g = rit&3;
        int r = g*128 + (mt>>2)*16 + lj*4 + (mt&3);
        int k = kt*32 + (l>>4)*8 + e;
        float v = (k < 128) ? wih1[r*128 + k] : whh1[r*128 + (k-128)];
        v *= (g==2) ? (2.f*L2E) : L2E;
        wb1[idx] = f2bf(v);
        return;
    }
    idx -= 131072;
    if (idx < 65536){
        int e = idx&7, l = (idx>>3)&63, hsel = (idx>>9)&1, kt = (idx>>10)&3,
            nt = (idx>>12)&7, mat = (idx>>15)&1;
        int fo = nt*16 + (l&15);
        int k  = kt*32 + (l>>4)*8 + e;
        float v = (mat ? glw2 : glw1)[fo*128 + k];
        unsigned short hb = f2bf(v);
        wpk[idx] = hsel ? f2bf(v - bf2f(hb)) : hb;
        return;
    }
    idx -= 65536;
    if (idx < 8192){
        int e = idx&7, l = (idx>>3)&63, kt = (idx>>9)&3, nt = (idx>>11)&3;
        int o = nt*16 + (l&15);
        int k = kt*32 + (l>>4)*8 + e;
        gpk[idx] = f2bf(gcn_w[k*64 + o]);
    }
}

// ---------------------------------------------------------------------------
// Kernel M: zmean[blk*288+u] = f2bf(mean over d of bf2f(zlin hi)).
// Bit-identical to the old in-kernB x2 path (f32 accumulate, d ascending).
// ---------------------------------------------------------------------------
__global__ __launch_bounds__(256) void kernM(
    const uint4* __restrict__ zlin, uint4* __restrict__ zmean)
{
    int idx = blockIdx.x*256 + threadIdx.x;
    if (idx >= GBLK*288) return;
    int blk = idx/288, u = idx - blk*288;
    int k8 = u>>5, sq = u&31;
    int gs = blk*32 + sq, bb = gs&255, nn = gs>>8;
    const uint4* src = zlin + (size_t)bb*DD*414 + nn*18 + k8;
    float s[8];
    #pragma unroll
    for (int e=0;e<8;e++) s[e]=0.f;
    for (int d=0; d<DD; ++d){
        uint4 v = src[(size_t)d*414];
        const unsigned short* hp = (const unsigned short*)&v;
        #pragma unroll
        for (int e=0;e<8;e++) s[e] += bf2f(hp[e]);
    }
    __align__(16) unsigned short ob[8];
    #pragma unroll
    for (int e=0;e<8;e++) ob[e] = f2bf(s[e]*(1.f/(float)DD));
    zmean[idx] = *(const uint4*)ob;
}

// ---------------------------------------------------------------------------
// Kernel A (unchanged R20): per-(b,d) graph stage -> adj + zlin[bd][414].
// ---------------------------------------------------------------------------
__global__ __launch_bounds__(256) void kernA(
    const float* __restrict__ x, const float* __restrict__ adj_real,
    const float* __restrict__ infection, const int* __restrict__ day_order,
    const float* __restrict__ b1, const float* __restrict__ b2,
    const float* __restrict__ glp, const float* __restrict__ vvec,
    const v8bf* __restrict__ wpk, const v8bf* __restrict__ gpk,
    float* __restrict__ out_adj, uint4* __restrict__ zlin4)
{
    const int bd = blockIdx.x;
    const int b  = bd / DD;
    const int t  = threadIdx.x;
    const int w  = t>>6, l = t&63;

    __shared__ float sm[4140];
    const int S12=0, ADJ=552, XW=1104, DEG=2576, DINV=2599, FACT=2622,
              INFS=2645, GC=2668;
    __shared__ __align__(16) unsigned short xhl[2][32][140];
    __shared__ __align__(16) unsigned short n1b[32*136];
    __shared__ __align__(16) unsigned short n2b[32*136];
    unsigned short* n1l = &xhl[0][0][0];
    unsigned short* n2l = n1l + 32*136;

    {
        const float4* xg4 = (const float4*)(x + (size_t)bd*(DN*DF));
        for (int p=t; p<736; p+=256){
            float4 v = xg4[p];
            int n = p>>5, k4 = (p&31)<<2;
            unsigned short h0=f2bf(v.x), h1=f2bf(v.y), h2=f2bf(v.z), h3=f2bf(v.w);
            u16x4 hv = {h0,h1,h2,h3};
            u16x4 lv = {f2bf(v.x-bf2f(h0)), f2bf(v.y-bf2f(h1)),
                        f2bf(v.z-bf2f(h2)), f2bf(v.w-bf2f(h3))};
            *(u16x4*)&xhl[0][n][k4] = hv;
            *(u16x4*)&xhl[1][n][k4] = lv;
        }
    }
    for (int p=t; p<9*DF; p+=256){
        int n = DN + (p>>7), k = p&127;
        xhl[0][n][k] = 0; xhl[1][n][k] = 0;
    }
    {
        const float* arg = adj_real + (size_t)bd*(DN*DN);
        for (int p=t; p<DN*DN; p+=256){
            int i = p/DN, j = p - i*DN;
            sm[ADJ + i*24 + j] = arg[p];
        }
    }
    {
        uint4 z; z.x=z.y=z.z=z.w=0u;
        for (int i=t; i<306; i+=256){
            int bsel = (i >= 153), off = bsel ? i-153 : i;
            *(uint4*)((char*)(bsel ? n2b : n1b) + 6256 + off*16) = z;
        }
    }
    if (t < DN){
        float vv = vvec[t];
        sm[FACT+t] = __expf(vv*vv*(float)day_order[b]);
        sm[INFS+t] = infection[(size_t)bd*DN + t];
    }
    __syncthreads();

    {
        f32x4 acc2[2];
        { f32x4 z; z[0]=z[1]=z[2]=z[3]=0.f; acc2[0]=z; acc2[1]=z; }
        #pragma unroll
        for (int kt=0;kt<4;kt++){
            v8bf ah[2], al[2];
            #pragma unroll
            for (int mt=0;mt<2;mt++){
                int m = mt*16 + (l&15);
                int ko = (l>>4)*8 + kt*32;
                ah[mt] = *(const v8bf*)&xhl[0][m][ko];
                al[mt] = *(const v8bf*)&xhl[1][m][ko];
            }
            v8bf gh = gpk[(size_t)(w*4+kt)*64 + l];
            MFMA_(acc2[0], ah[0], gh);
            MFMA_(acc2[1], ah[1], gh);
            MFMA_(acc2[0], al[0], gh);
            MFMA_(acc2[1], al[1], gh);
        }
        int o = w*16 + (l&15);
        #pragma unroll
        for (int mt=0;mt<2;mt++){
            #pragma unroll
            for (int r=0;r<4;r++){
                int n = mt*16 + (l>>4)*4 + r;
                if (n < DN) sm[XW + n*64 + o] = acc2[mt][r];
            }
        }
    }

    if (t < DN){
        float s = 0.f;
        for (int m=0;m<DN;m++) s += sm[ADJ + t*24 + m];
        sm[DEG+t] = s;
    }

    {
        const int mat = w>>1;
        const int ntb = (w&1)*4;
        const float* bsrc = mat ? b2 : b1;
        float bias[4];
        #pragma unroll
        for (int q=0;q<4;q++) bias[q] = bsrc[(ntb+q)*16 + (l&15)];
        f32x4 acc[2][4];
        #pragma unroll
        for (int mt=0;mt<2;mt++)
            #pragma unroll
            for (int q=0;q<4;q++){ f32x4 z; z[0]=z[1]=z[2]=z[3]=0.f; acc[mt][q]=z; }
        #pragma unroll
        for (int kt=0;kt<4;kt++){
            v8bf ah[2], al[2];
            #pragma unroll
            for (int mt=0;mt<2;mt++){
                int m = mt*16 + (l&15);
                int ko = (l>>4)*8 + kt*32;
                ah[mt] = *(const v8bf*)&xhl[0][m][ko];
                al[mt] = *(const v8bf*)&xhl[1][m][ko];
            }
            #pragma unroll
            for (int q=0;q<4;q++){
                const v8bf* wb = wpk + ((size_t)(((mat*8+(ntb+q))*4+kt)*2)*64 + l);
                v8bf wh = wb[0], wl = wb[64];
                MFMA_(acc[0][q], ah[0], wh);
                MFMA_(acc[1][q], ah[1], wh);
                MFMA_(acc[0][q], al[0], wh);
                MFMA_(acc[1][q], al[1], wh);
                MFMA_(acc[0][q], ah[0], wl);
                MFMA_(acc[1][q], ah[1], wl);
            }
        }
        __syncthreads();

        unsigned short* dsth = mat ? n2b : n1b;
        unsigned short* dstl = mat ? n2l : n1l;
        #pragma unroll
        for (int mt=0;mt<2;mt++){
            #pragma unroll
            for (int q=0;q<4;q++){
                int fo = (ntb+q)*16 + (l&15);
                #pragma unroll
                for (int r=0;r<4;r++){
                    int n = mt*16 + (l>>4)*4 + r;
                    if (n < DN){
                        float nv = ftanhR(acc[mt][q][r] + bias[q]);
                        unsigned short hb = f2bf(nv);
                        dsth[n*136 + fo] = hb;
                        dstl[n*136 + fo] = f2bf(nv - bf2f(hb));
                    }
                }
            }
        }
        {
            uint4 z; z.x=z.y=z.z=z.w=0u;
            for (int i=t; i<306; i+=256){
                int bsel = (i >= 153), off = bsel ? i-153 : i;
                *(uint4*)((char*)(bsel ? n2l : n1l) + 6256 + off*16) = z;
            }
        }
    }
    __syncthreads();

    {
        const int mt = w>>1, nt = w&1;
        f32x4 a3; a3[0]=a3[1]=a3[2]=a3[3]=0.f;
        #pragma unroll
        for (int kt=0;kt<4;kt++){
            int ar = (mt*16+(l&15))*136 + kt*32 + (l>>4)*8;
            int br = (nt*16+(l&15))*136 + kt*32 + (l>>4)*8;
            v8bf ah  = *(const v8bf*)&n1b[ar];
            v8bf alo = *(const v8bf*)&n1l[ar];
            v8bf bh  = *(const v8bf*)&n2b[br];
            v8bf blo = *(const v8bf*)&n2l[br];
            MFMA_(a3, ah,  bh);
            MFMA_(a3, alo, bh);
            MFMA_(a3, ah,  blo);
        }
        #pragma unroll
        for (int r=0;r<4;r++){
            int i = mt*16 + (l>>4)*4 + r;
            int j = nt*16 + (l&15);
            if (i < DN && j < DN) sm[S12 + i*24 + j] = a3[r];
        }
    }
    __syncthreads();

    for (int p=t; p<DN*DN; p+=256){
        int i=p/DN, j=p-i*DN;
        float al  = fmaxf(ftanhR(sm[S12+i*24+j]-sm[S12+j*24+i]), 0.f);
        float md  = fsigR(glp[i*DN+j]*sm[DEG+i]*sm[DEG+j]);
        float arv = sm[ADJ + i*24 + j];
        float adjv = al + md*arv;
        __builtin_nontemporal_store(adjv, &out_adj[(size_t)bd*(DN*DN) + p]);
        sm[ADJ + i*24 + j] = adjv + (i==j ? 1.f : 0.f);
    }
    __syncthreads();

    if (t<DN){
        float rs=0.f;
        for (int jj=0;jj<DN;jj++) rs += sm[ADJ+t*24+jj];
        sm[DINV+t] = rsqrtf(rs);
    }
    __syncthreads();

    for (int p=t;p<DN*DN;p+=256){
        int i=p/DN, j=p-i*DN;
        sm[ADJ+i*24+j] *= sm[DINV+i]*sm[DINV+j];
    }
    __syncthreads();

    for (int p=t;p<DN*64;p+=256){
        int n=p>>6, o=p&63;
        float a=0.f;
        #pragma unroll
        for (int m=0;m<DN;m++) a = fmaf(sm[ADJ+n*24+m], sm[XW+m*64+o], a);
        sm[GC + p] = fmaxf(a,0.f)*sm[FACT+n];
    }
    __syncthreads();

    for (int p=t; p<DN*18; p+=256){
        int n = p/18, r = p - n*18, hsel = r/9, k8 = r - hsel*9;
        __align__(16) unsigned short ob[8];
        #pragma unroll
        for (int e=0;e<8;e++){
            int k = k8*8+e;
            float v = (k<64) ? sm[GC + n*64 + k] : ((k==64) ? sm[INFS+n] : 0.f);
            unsigned short hb = f2bf(v);
            ob[e] = hsel ? f2bf(v - bf2f(hb)) : hb;
        }
        zlin4[(size_t)bd*414 + p] = *(const uint4*)ob;
    }
}

// ---------------------------------------------------------------------------
// Kernel B: MFMA LSTM.  grid=184, block=1024 (16 waves), 32 seqs/block.
// R21: no X2 machinery (kernM supplies zmean via normal staging path);
// L1 kt=0 weights prefetched pre-barrier; LDS 83KB.
// ---------------------------------------------------------------------------
#define XB0O 0
#define XB1O 4608
#define U1H0 9216           // 2 x 9728 -> 28672
#define U1H1 28672          // 2 x 8192 -> 45056
#define B0O  45056          // 512 f32 -> 47104
#define B1O  47104          // -> 49152
#define FCO  49152          // 129 f32 -> 49668 (pad 49680)
#define INO  49680          // 32 f32 -> 49808
#define C0O  49808          // 16384 -> 66192
#define C1O  66192          // 16384 -> 82576
// end 82576

__global__ __launch_bounds__(1024, 2) void kernB(
    const uint4* __restrict__ zlin, const uint4* __restrict__ zmean,
    const v8bf* __restrict__ w0p, const v8bf* __restrict__ w1p,
    const float* __restrict__ b0g, const float* __restrict__ b1g,
    const float* __restrict__ infection, const float* __restrict__ fcw,
    const float* __restrict__ fcb, float* __restrict__ outy)
{
    const int t = threadIdx.x, blk = blockIdx.x;
    const int w = t>>6, l = t&63;
    const int lhi = l>>4, llo = l&15;
    __shared__ __align__(16) unsigned char smraw[82576];
    char* smb = (char*)smraw;

    // zero h surfaces (9216..45056) and c-slots (49808..82576)
    {
        uint4 z; z.x=z.y=z.z=z.w=0u;
        for (int i = t; i < (45056-9216)/16; i += 1024) ((uint4*)(smb+9216))[i] = z;
        for (int i = t; i < (82576-49808)/16; i += 1024) ((uint4*)(smb+49808))[i] = z;
    }
    if (t < 512){
        float s = ((t&3)==2) ? (2.f*L2E) : L2E;
        ((float*)(smb+B0O))[t] = b0g[(t&3)*128 + (t>>2)] * s;
        ((float*)(smb+B1O))[t] = b1g[(t&3)*128 + (t>>2)] * s;
    }
    if (t < 129) ((float*)(smb+FCO))[t] = (t<128) ? fcw[t] : fcb[0];
    if (t < 32){
        int gseq = blk*32 + t, n = gseq>>8, bb = gseq&255;
        float a = 0.f;
        for (int dd=0; dd<DD; dd++)
            a = fmaf(fcw[128+dd], infection[((size_t)bb*DD+dd)*DN+n], a);
        ((float*)(smb+INO))[t] = a;
    }

    int k81 = t >> 5, sq1 = t & 31;
    int gs1 = blk*32 + sq1;
    size_t cb1 = (size_t)(gs1 & 255)*DD*414 + (gs1>>8)*18 + k81;   // hsel=0
    int d1 = t*16;
    const uint4* zme = zmean + (size_t)blk*288 + t;                // t<288 only

    const int mt0 = 2*w;
    const int jt  = mt0>>2, r3 = mt0&3;
    const int j8  = jt*2 + (lhi>>1);
    const int sub = (lhi&1)*8 + r3*2;
    const int j0  = jt*16 + lhi*4 + r3;

    __syncthreads();

    if (t < 288){
        uint4 a0 = ntload4(zlin + cb1);
        *(uint4*)(smb + XB0O + d1) = a0;
    }
    __syncthreads();

    for (int step = 0; step < DD + DY; ++step){
        const int ps  = step & 1;
        const int xb  = ps ? XB1O : XB0O;
        const int xbn = ps ? XB0O : XB1O;
        const bool do_stage = (step + 1 < DD + DY);
        const char* h0rd = smb + U1H0 + (ps^1)*9728;
        char*       h0wr = smb + U1H0 + ps*9728;
        const char* h1rd = smb + U1H1 + (ps^1)*8192;
        char*       h1wr = smb + U1H1 + ps*8192;

        v8bf P0, P1;   // L1 kt=0 weight prefetch (issued pre-barrier)

        // ---------------- L0 MFMA (+ stage x(step+1)) ----------------
        {
            uint4 sv0; sv0.x=sv0.y=sv0.z=sv0.w=0u;
            if (do_stage && t < 288){
                const uint4* src = (step+1 < DD) ? (zlin + (size_t)(step+1)*414 + cb1)
                                                 : zme;
                sv0 = ntload4(src);
            }

            f32x4 acc[2][2];
            #pragma unroll
            for (int mi=0;mi<2;mi++){
                f32x4 bv = *(const f32x4*)(smb + B0O + (j0+mi)*16);
                acc[mi][0] = bv; acc[mi][1] = bv;
            }
            #pragma unroll 2
            for (int kt=0; kt<7; ++kt){
                const v8bf* wrow = w0p + (size_t)(kt*32 + mt0)*64 + l;
                v8bf A0 = wrow[0], A1 = wrow[64];
                int k8 = kt*4 + lhi;
                bool inx = (k8 <= 8);
                const char* hib = inx ? (smb + xb + k8*512) : (h0rd + (k8-9)*512);
                v8bf BH0 = *(const v8bf*)(hib + llo*16);
                v8bf BH1 = *(const v8bf*)(hib + 256 + llo*16);
                MFMA_(acc[0][0], A0, BH0);
                MFMA_(acc[1][0], A1, BH0);
                MFMA_(acc[0][1], A0, BH1);
                MFMA_(acc[1][1], A1, BH1);
            }

            // prefetch L1 kt=0 A-frags (global; overlaps ACT + barrier wait)
            {
                const v8bf* w1r0 = w1p + (size_t)mt0*64 + l;
                P0 = w1r0[0]; P1 = w1r0[64];
            }

            if (do_stage && t < 288)
                *(uint4*)(smb + xbn + d1) = sv0;

            // ACT L0 (raw exp2/rcp)
            {
                f32x4 c0v = *(const f32x4*)(smb + C0O + t*16);
                #pragma unroll
                for (int nt=0;nt<2;nt++){
                    float hf[2];
                    #pragma unroll
                    for (int mi=0;mi<2;mi++){
                        f32x4 a = acc[mi][nt];
                        float ii = fsig2(a[0]), ff = fsig2(a[1]), gg = ftanh2(a[2]), oo = fsig2(a[3]);
                        float c = ff*c0v[mi*2+nt] + ii*gg;
                        c0v[mi*2+nt] = c;
                        hf[mi] = oo*ftanhc(c);
                    }
                    unsigned ph = pkbf(hf[0], hf[1]);
                    int bo = j8*512 + (nt*16+llo)*16 + sub;
                    *(unsigned*)(h0wr + bo) = ph;
                }
                *(f32x4*)(smb + C0O + t*16) = c0v;
            }
            __syncthreads();   // THE barrier
        }

        // ---------------- L1 MFMA (kt=0 peeled, weights prefetched) ----------
        {
            f32x4 acc1[2][2];
            #pragma unroll
            for (int mi=0;mi<2;mi++){
                f32x4 bv = *(const f32x4*)(smb + B1O + (j0+mi)*16);
                acc1[mi][0] = bv; acc1[mi][1] = bv;
            }
            {   // kt = 0: k8 = lhi < 16 -> h0wr
                const char* hib = h0wr + lhi*512;
                v8bf BH0 = *(const v8bf*)(hib + llo*16);
                v8bf BH1 = *(const v8bf*)(hib + 256 + llo*16);
                MFMA_(acc1[0][0], P0, BH0);
                MFMA_(acc1[1][0], P1, BH0);
                MFMA_(acc1[0][1], P0, BH1);
                MFMA_(acc1[1][1], P1, BH1);
            }
            #pragma unroll 2
            for (int kt=1; kt<8; ++kt){
                const v8bf* wrow = w1p + (size_t)(kt*32 + mt0)*64 + l;
                v8bf A0 = wrow[0], A1 = wrow[64];
                int k8 = kt*4 + lhi;
                const char* hib = (k8 < 16) ? (h0wr + k8*512) : (h1rd + (k8-16)*512);
                v8bf BH0 = *(const v8bf*)(hib + llo*16);
                v8bf BH1 = *(const v8bf*)(hib + 256 + llo*16);
                MFMA_(acc1[0][0], A0, BH0);
                MFMA_(acc1[1][0], A1, BH0);
                MFMA_(acc1[0][1], A0, BH1);
                MFMA_(acc1[1][1], A1, BH1);
            }

            // ACT L1 (raw exp2/rcp)
            {
                f32x4 c1v = *(const f32x4*)(smb + C1O + t*16);
                #pragma unroll
                for (int nt=0;nt<2;nt++){
                    float hf[2];
                    #pragma unroll
                    for (int mi=0;mi<2;mi++){
                        f32x4 a = acc1[mi][nt];
                        float ii = fsig2(a[0]), ff = fsig2(a[1]), gg = ftanh2(a[2]), oo = fsig2(a[3]);
                        float c = ff*c1v[mi*2+nt] + ii*gg;
                        c1v[mi*2+nt] = c;
                        hf[mi] = oo*ftanhc(c);
                    }
                    unsigned ph = pkbf(hf[0], hf[1]);
                    int bo = j8*512 + (nt*16+llo)*16 + sub;
                    *(unsigned*)(h1wr + bo) = ph;
                }
                *(f32x4*)(smb + C1O + t*16) = c1v;
            }
        }

        // ---- decoder FC (reads h1(step) = U1H1[ps])
        if (step >= DD){
            __syncthreads();
            if (t < 256){
                int seq = t>>3, l8 = t&7;
                const unsigned short* uh = (const unsigned short*)(smb + U1H1 + ps*8192);
                const float* fw = (const float*)(smb+FCO);
                float a = 0.f;
                #pragma unroll
                for (int half=0; half<2; ++half){
                    int k8 = l8*2 + half;
                    int base = (k8*32 + seq)*8;
                    #pragma unroll
                    for (int e=0;e<8;e++){
                        int j = l8*16 + half*8 + e;
                        a = fmaf(fw[j], bf2f(uh[base+e]), a);
                    }
                }
                a += __shfl_down(a, 4, 8);
                a += __shfl_down(a, 2, 8);
                a += __shfl_down(a, 1, 8);
                if (l8 == 0){
                    int gseq = blk*32 + seq, n = gseq>>8, bb = gseq&255;
                    float yv = fmaxf(a + ((const float*)(smb+INO))[seq] + fw[128], 0.f);
                    __builtin_nontemporal_store(yv, &outy[((size_t)bb*DY + (step-DD))*DN + n]);
                }
            }
        }
    }
}

// ---------------------------------------------------------------------------
extern "C" void kernel_launch(void* const* d_in, const int* in_sizes, int n_in,
                              void* d_out, int out_size, void* d_ws, size_t ws_size,
                              hipStream_t stream)
{
    const float* x         = (const float*)d_in[0];
    const float* adj_real  = (const float*)d_in[1];
    const float* infection = (const float*)d_in[2];
    const int*   day_order = (const int*)  d_in[3];
    const float* gl_w1     = (const float*)d_in[4];
    const float* gl_b1     = (const float*)d_in[5];
    const float* gl_w2     = (const float*)d_in[6];
    const float* gl_b2     = (const float*)d_in[7];
    const float* glp       = (const float*)d_in[8];
    const float* gcn_w     = (const float*)d_in[9];
    const float* vvec      = (const float*)d_in[10];
    const float* wih0      = (const float*)d_in[11];
    const float* whh0      = (const float*)d_in[12];
    const float* b0        = (const float*)d_in[13];
    const float* wih1      = (const float*)d_in[14];
    const float* whh1      = (const float*)d_in[15];
    const float* b1        = (const float*)d_in[16];
    const float* fcw       = (const float*)d_in[17];
    const float* fcb       = (const float*)d_in[18];

    uint8_t* wsb = (uint8_t*)d_ws;
    uint4*          zlin  = (uint4*)(wsb);
    unsigned short* wb0   = (unsigned short*)(wsb + WB0_OFF);
    unsigned short* wb1   = (unsigned short*)(wsb + WB1_OFF);
    unsigned short* wpk   = (unsigned short*)(wsb + WPK_OFF);
    unsigned short* gpk   = (unsigned short*)(wsb + GPK_OFF);
    uint4*          zmean = (uint4*)(wsb + ZME_OFF);
    float* out_adj = (float*)d_out;
    float* out_y   = out_adj + ADJSZ;

    kernPrep<<<dim3(1248), dim3(256), 0, stream>>>(wih0, whh0, wih1, whh1,
                                                   gl_w1, gl_w2, gcn_w,
                                                   wb0, wb1, wpk, gpk);
    kernA<<<dim3(DB*DD), dim3(256), 0, stream>>>(x, adj_real, infection, day_order,
                                                 gl_b1, gl_b2, glp, vvec,
                                                 (const v8bf*)wpk, (const v8bf*)gpk,
                                                 out_adj, zlin);
    kernM<<<dim3((GBLK*288+255)/256), dim3(256), 0, stream>>>(zlin, zmean);
    kernB<<<dim3(GBLK), dim3(1024), 0, stream>>>(zlin, zmean, (const v8bf*)wb0,
                                                 (const v8bf*)wb1, b0, b1, infection,
                                                 fcw, fcb, out_y);
}

// Round 22
// 294.235 us; speedup vs baseline: 1.0311x; 1.0311x over previous
//
#include <hip/hip_runtime.h>
#include <hip/hip_bf16.h>
#include <stdint.h>

// ---------------------------------------------------------------------------
// B=256 D=28 N=23 F=128 O=64 H=128 Y=7.  NBSEQ=5888 = 184 blocks x 32 seqs.
// R22 (final): R20 structure (3 kernels, x2 in kernB) + R21's proven L1-kt0
// weight prefetch (pre-barrier issue, peeled first L1 iteration).
// History: 2190us (R1 f32) -> 297us (R20); key levers: MFMA everywhere,
// spill elimination (unroll-1/2 + LDS state), 1-barrier step schedule,
// hi-only bf16 operands, raw v_exp/v_rcp activations, vectorized staging.
// ---------------------------------------------------------------------------

#define DB 256
#define DD 28
#define DN 23
#define DF 128
#define DO 64
#define DH 128
#define DY 7
#define NBSEQ (DN*DB)
#define ADJSZ (DB*DD*DN*DN)
#define GBLK 184
#define L2E 1.4426950408889634f

// workspace byte offsets
#define WB0_OFF   47480832u            // zlin = 7168*414*16
#define WB1_OFF   47710208u
#define WPK_OFF   47972352u
#define GPK_OFF   48103424u

using v8bf  = __attribute__((ext_vector_type(8))) __bf16;
using f32x4 = __attribute__((ext_vector_type(4))) float;
using u32x4 = __attribute__((ext_vector_type(4))) unsigned int;
using u16x4 = __attribute__((ext_vector_type(4))) unsigned short;

__device__ __forceinline__ float fsig(float x)  { return 1.f/(1.f+__expf(-x)); }
__device__ __forceinline__ float ftanh(float x) { return 1.f - 2.f/(__expf(2.f*x)+1.f); }
__device__ __forceinline__ float fsigR(float x){
    return __builtin_amdgcn_rcpf(1.f + __builtin_amdgcn_exp2f(-x*L2E));
}
__device__ __forceinline__ float ftanhR(float x){
    return 1.f - 2.f*__builtin_amdgcn_rcpf(__builtin_amdgcn_exp2f(x*(2.f*L2E))+1.f);
}
__device__ __forceinline__ float fsig2(float a){
    return __builtin_amdgcn_rcpf(1.f + __builtin_amdgcn_exp2f(-a));
}
__device__ __forceinline__ float ftanh2(float a){
    return 1.f - 2.f*__builtin_amdgcn_rcpf(__builtin_amdgcn_exp2f(a)+1.f);
}
__device__ __forceinline__ float ftanhc(float c){
    return 1.f - 2.f*__builtin_amdgcn_rcpf(__builtin_amdgcn_exp2f(c*(2.f*L2E))+1.f);
}

__device__ __forceinline__ unsigned short f2bf(float f){
    unsigned u = __builtin_bit_cast(unsigned, f);
    return (unsigned short)((u + 0x7FFFu + ((u>>16)&1u)) >> 16);
}
__device__ __forceinline__ float bf2f(unsigned short b){
    return __builtin_bit_cast(float, (unsigned)b << 16);
}
__device__ __forceinline__ uint4 ntload4(const uint4* p){
    u32x4 v = __builtin_nontemporal_load((const u32x4*)p);
    return *(uint4*)&v;
}
__device__ __forceinline__ unsigned pkbf(float lo, float hi){
    unsigned r;
    asm("v_cvt_pk_bf16_f32 %0, %1, %2" : "=v"(r) : "v"(lo), "v"(hi));
    return r;
}

#define MFMA_(acc_, A_, B_) acc_ = __builtin_amdgcn_mfma_f32_16x16x32_bf16(A_, B_, acc_, 0, 0, 0)

// ---------------------------------------------------------------------------
// Prep (R17/R18: LSTM rows prescaled; g-gate by 2*log2e, others log2e)
// ---------------------------------------------------------------------------
__global__ __launch_bounds__(256) void kernPrep(
    const float* __restrict__ wih0, const float* __restrict__ whh0,
    const float* __restrict__ wih1, const float* __restrict__ whh1,
    const float* __restrict__ glw1, const float* __restrict__ glw2,
    const float* __restrict__ gcn_w,
    unsigned short* __restrict__ wb0, unsigned short* __restrict__ wb1,
    unsigned short* __restrict__ wpk, unsigned short* __restrict__ gpk)
{
    int idx = blockIdx.x*256 + threadIdx.x;
    if (idx < 114688){
        int e = idx&7, l = (idx>>3)&63, mt = (idx>>9)&31, kt = idx>>14;
        int rit = l&15, lj = rit>>2, g = rit&3;
        int r = g*128 + (mt>>2)*16 + lj*4 + (mt&3);
        int k = kt*32 + (l>>4)*8 + e;
        float v = 0.f;
        if (k < 65)                  v = wih0[r*65 + k];
        else if (k >= 72 && k < 200) v = whh0[r*128 + (k-72)];
        v *= (g==2) ? (2.f*L2E) : L2E;
        wb0[idx] = f2bf(v);
        return;
    }
    idx -= 114688;
    if (idx < 131072){
        int e = idx&7, l = (idx>>3)&63, mt = (idx>>9)&31, kt = idx>>14;
        int rit = l&15, lj = rit>>2, g = rit&3;
        int r = g*128 + (mt>>2)*16 + lj*4 + (mt&3);
        int k = kt*32 + (l>>4)*8 + e;
        float v = (k < 128) ? wih1[r*128 + k] : whh1[r*128 + (k-128)];
        v *= (g==2) ? (2.f*L2E) : L2E;
        wb1[idx] = f2bf(v);
        return;
    }
    idx -= 131072;
    if (idx < 65536){
        int e = idx&7, l = (idx>>3)&63, hsel = (idx>>9)&1, kt = (idx>>10)&3,
            nt = (idx>>12)&7, mat = (idx>>15)&1;
        int fo = nt*16 + (l&15);
        int k  = kt*32 + (l>>4)*8 + e;
        float v = (mat ? glw2 : glw1)[fo*128 + k];
        unsigned short hb = f2bf(v);
        wpk[idx] = hsel ? f2bf(v - bf2f(hb)) : hb;
        return;
    }
    idx -= 65536;
    if (idx < 8192){
        int e = idx&7, l = (idx>>3)&63, kt = (idx>>9)&3, nt = (idx>>11)&3;
        int o = nt*16 + (l&15);
        int k = kt*32 + (l>>4)*8 + e;
        gpk[idx] = f2bf(gcn_w[k*64 + o]);
    }
}

// ---------------------------------------------------------------------------
// Kernel A (R20): per-(b,d) graph stage -> adj + zlin[bd][414].
// ---------------------------------------------------------------------------
__global__ __launch_bounds__(256) void kernA(
    const float* __restrict__ x, const float* __restrict__ adj_real,
    const float* __restrict__ infection, const int* __restrict__ day_order,
    const float* __restrict__ b1, const float* __restrict__ b2,
    const float* __restrict__ glp, const float* __restrict__ vvec,
    const v8bf* __restrict__ wpk, const v8bf* __restrict__ gpk,
    float* __restrict__ out_adj, uint4* __restrict__ zlin4)
{
    const int bd = blockIdx.x;
    const int b  = bd / DD;
    const int t  = threadIdx.x;
    const int w  = t>>6, l = t&63;

    __shared__ float sm[4140];
    const int S12=0, ADJ=552, XW=1104, DEG=2576, DINV=2599, FACT=2622,
              INFS=2645, GC=2668;
    __shared__ __align__(16) unsigned short xhl[2][32][140];
    __shared__ __align__(16) unsigned short n1b[32*136];
    __shared__ __align__(16) unsigned short n2b[32*136];
    unsigned short* n1l = &xhl[0][0][0];
    unsigned short* n2l = n1l + 32*136;

    {
        const float4* xg4 = (const float4*)(x + (size_t)bd*(DN*DF));
        for (int p=t; p<736; p+=256){
            float4 v = xg4[p];
            int n = p>>5, k4 = (p&31)<<2;
            unsigned short h0=f2bf(v.x), h1=f2bf(v.y), h2=f2bf(v.z), h3=f2bf(v.w);
            u16x4 hv = {h0,h1,h2,h3};
            u16x4 lv = {f2bf(v.x-bf2f(h0)), f2bf(v.y-bf2f(h1)),
                        f2bf(v.z-bf2f(h2)), f2bf(v.w-bf2f(h3))};
            *(u16x4*)&xhl[0][n][k4] = hv;
            *(u16x4*)&xhl[1][n][k4] = lv;
        }
    }
    for (int p=t; p<9*DF; p+=256){
        int n = DN + (p>>7), k = p&127;
        xhl[0][n][k] = 0; xhl[1][n][k] = 0;
    }
    {
        const float* arg = adj_real + (size_t)bd*(DN*DN);
        for (int p=t; p<DN*DN; p+=256){
            int i = p/DN, j = p - i*DN;
            sm[ADJ + i*24 + j] = arg[p];
        }
    }
    {
        uint4 z; z.x=z.y=z.z=z.w=0u;
        for (int i=t; i<306; i+=256){
            int bsel = (i >= 153), off = bsel ? i-153 : i;
            *(uint4*)((char*)(bsel ? n2b : n1b) + 6256 + off*16) = z;
        }
    }
    if (t < DN){
        float vv = vvec[t];
        sm[FACT+t] = __expf(vv*vv*(float)day_order[b]);
        sm[INFS+t] = infection[(size_t)bd*DN + t];
    }
    __syncthreads();

    {
        f32x4 acc2[2];
        { f32x4 z; z[0]=z[1]=z[2]=z[3]=0.f; acc2[0]=z; acc2[1]=z; }
        #pragma unroll
        for (int kt=0;kt<4;kt++){
            v8bf ah[2], al[2];
            #pragma unroll
            for (int mt=0;mt<2;mt++){
                int m = mt*16 + (l&15);
                int ko = (l>>4)*8 + kt*32;
                ah[mt] = *(const v8bf*)&xhl[0][m][ko];
                al[mt] = *(const v8bf*)&xhl[1][m][ko];
            }
            v8bf gh = gpk[(size_t)(w*4+kt)*64 + l];
            MFMA_(acc2[0], ah[0], gh);
            MFMA_(acc2[1], ah[1], gh);
            MFMA_(acc2[0], al[0], gh);
            MFMA_(acc2[1], al[1], gh);
        }
        int o = w*16 + (l&15);
        #pragma unroll
        for (int mt=0;mt<2;mt++){
            #pragma unroll
            for (int r=0;r<4;r++){
                int n = mt*16 + (l>>4)*4 + r;
                if (n < DN) sm[XW + n*64 + o] = acc2[mt][r];
            }
        }
    }

    if (t < DN){
        float s = 0.f;
        for (int m=0;m<DN;m++) s += sm[ADJ + t*24 + m];
        sm[DEG+t] = s;
    }

    {
        const int mat = w>>1;
        const int ntb = (w&1)*4;
        const float* bsrc = mat ? b2 : b1;
        float bias[4];
        #pragma unroll
        for (int q=0;q<4;q++) bias[q] = bsrc[(ntb+q)*16 + (l&15)];
        f32x4 acc[2][4];
        #pragma unroll
        for (int mt=0;mt<2;mt++)
            #pragma unroll
            for (int q=0;q<4;q++){ f32x4 z; z[0]=z[1]=z[2]=z[3]=0.f; acc[mt][q]=z; }
        #pragma unroll
        for (int kt=0;kt<4;kt++){
            v8bf ah[2], al[2];
            #pragma unroll
            for (int mt=0;mt<2;mt++){
                int m = mt*16 + (l&15);
                int ko = (l>>4)*8 + kt*32;
                ah[mt] = *(const v8bf*)&xhl[0][m][ko];
                al[mt] = *(const v8bf*)&xhl[1][m][ko];
            }
            #pragma unroll
            for (int q=0;q<4;q++){
                const v8bf* wb = wpk + ((size_t)(((mat*8+(ntb+q))*4+kt)*2)*64 + l);
                v8bf wh = wb[0], wl = wb[64];
                MFMA_(acc[0][q], ah[0], wh);
                MFMA_(acc[1][q], ah[1], wh);
                MFMA_(acc[0][q], al[0], wh);
                MFMA_(acc[1][q], al[1], wh);
                MFMA_(acc[0][q], ah[0], wl);
                MFMA_(acc[1][q], ah[1], wl);
            }
        }
        __syncthreads();

        unsigned short* dsth = mat ? n2b : n1b;
        unsigned short* dstl = mat ? n2l : n1l;
        #pragma unroll
        for (int mt=0;mt<2;mt++){
            #pragma unroll
            for (int q=0;q<4;q++){
                int fo = (ntb+q)*16 + (l&15);
                #pragma unroll
                for (int r=0;r<4;r++){
                    int n = mt*16 + (l>>4)*4 + r;
                    if (n < DN){
                        float nv = ftanhR(acc[mt][q][r] + bias[q]);
                        unsigned short hb = f2bf(nv);
                        dsth[n*136 + fo] = hb;
                        dstl[n*136 + fo] = f2bf(nv - bf2f(hb));
                    }
                }
            }
        }
        {
            uint4 z; z.x=z.y=z.z=z.w=0u;
            for (int i=t; i<306; i+=256){
                int bsel = (i >= 153), off = bsel ? i-153 : i;
                *(uint4*)((char*)(bsel ? n2l : n1l) + 6256 + off*16) = z;
            }
        }
    }
    __syncthreads();

    {
        const int mt = w>>1, nt = w&1;
        f32x4 a3; a3[0]=a3[1]=a3[2]=a3[3]=0.f;
        #pragma unroll
        for (int kt=0;kt<4;kt++){
            int ar = (mt*16+(l&15))*136 + kt*32 + (l>>4)*8;
            int br = (nt*16+(l&15))*136 + kt*32 + (l>>4)*8;
            v8bf ah  = *(const v8bf*)&n1b[ar];
            v8bf alo = *(const v8bf*)&n1l[ar];
            v8bf bh  = *(const v8bf*)&n2b[br];
            v8bf blo = *(const v8bf*)&n2l[br];
            MFMA_(a3, ah,  bh);
            MFMA_(a3, alo, bh);
            MFMA_(a3, ah,  blo);
        }
        #pragma unroll
        for (int r=0;r<4;r++){
            int i = mt*16 + (l>>4)*4 + r;
            int j = nt*16 + (l&15);
            if (i < DN && j < DN) sm[S12 + i*24 + j] = a3[r];
        }
    }
    __syncthreads();

    for (int p=t; p<DN*DN; p+=256){
        int i=p/DN, j=p-i*DN;
        float al  = fmaxf(ftanhR(sm[S12+i*24+j]-sm[S12+j*24+i]), 0.f);
        float md  = fsigR(glp[i*DN+j]*sm[DEG+i]*sm[DEG+j]);
        float arv = sm[ADJ + i*24 + j];
        float adjv = al + md*arv;
        __builtin_nontemporal_store(adjv, &out_adj[(size_t)bd*(DN*DN) + p]);
        sm[ADJ + i*24 + j] = adjv + (i==j ? 1.f : 0.f);
    }
    __syncthreads();

    if (t<DN){
        float rs=0.f;
        for (int jj=0;jj<DN;jj++) rs += sm[ADJ+t*24+jj];
        sm[DINV+t] = rsqrtf(rs);
    }
    __syncthreads();

    for (int p=t;p<DN*DN;p+=256){
        int i=p/DN, j=p-i*DN;
        sm[ADJ+i*24+j] *= sm[DINV+i]*sm[DINV+j];
    }
    __syncthreads();

    for (int p=t;p<DN*64;p+=256){
        int n=p>>6, o=p&63;
        float a=0.f;
        #pragma unroll
        for (int m=0;m<DN;m++) a = fmaf(sm[ADJ+n*24+m], sm[XW+m*64+o], a);
        sm[GC + p] = fmaxf(a,0.f)*sm[FACT+n];
    }
    __syncthreads();

    for (int p=t; p<DN*18; p+=256){
        int n = p/18, r = p - n*18, hsel = r/9, k8 = r - hsel*9;
        __align__(16) unsigned short ob[8];
        #pragma unroll
        for (int e=0;e<8;e++){
            int k = k8*8+e;
            float v = (k<64) ? sm[GC + n*64 + k] : ((k==64) ? sm[INFS+n] : 0.f);
            unsigned short hb = f2bf(v);
            ob[e] = hsel ? f2bf(v - bf2f(hb)) : hb;
        }
        zlin4[(size_t)bd*414 + p] = *(const uint4*)ob;
    }
}

// ---------------------------------------------------------------------------
// Kernel B (R20 + R21 prefetch): MFMA LSTM, 184 blocks x 1024 thr,
// 1 barrier/step, x2 in-kernel, L1-kt0 weights prefetched pre-barrier.
// ---------------------------------------------------------------------------
#define XB0O 0
#define XB1O 4608
#define U1H0 9216
#define U1H1 28672
#define X2O  45056
#define B0O  54272
#define B1O  56320
#define FCO  58368
#define INO  58896
#define C0O  59024
#define C1O  75408
// end 91792

__global__ __launch_bounds__(1024, 2) void kernB(
    const uint4* __restrict__ zlin, const v8bf* __restrict__ w0p, const v8bf* __restrict__ w1p,
    const float* __restrict__ b0g, const float* __restrict__ b1g,
    const float* __restrict__ infection, const float* __restrict__ fcw,
    const float* __restrict__ fcb, float* __restrict__ outy)
{
    const int t = threadIdx.x, blk = blockIdx.x;
    const int w = t>>6, l = t&63;
    const int lhi = l>>4, llo = l&15;
    __shared__ __align__(16) unsigned char smraw[91792];
    char* smb = (char*)smraw;

    {
        uint4 z; z.x=z.y=z.z=z.w=0u;
        for (int i = t; i < (54272-9216)/16; i += 1024) ((uint4*)(smb+9216))[i] = z;
        for (int i = t; i < (91792-59024)/16; i += 1024) ((uint4*)(smb+59024))[i] = z;
    }
    if (t < 512){
        float s = ((t&3)==2) ? (2.f*L2E) : L2E;
        ((float*)(smb+B0O))[t] = b0g[(t&3)*128 + (t>>2)] * s;
        ((float*)(smb+B1O))[t] = b1g[(t&3)*128 + (t>>2)] * s;
    }
    if (t < 129) ((float*)(smb+FCO))[t] = (t<128) ? fcw[t] : fcb[0];
    if (t < 32){
        int gseq = blk*32 + t, n = gseq>>8, bb = gseq&255;
        float a = 0.f;
        for (int dd=0; dd<DD; dd++)
            a = fmaf(fcw[128+dd], infection[((size_t)bb*DD+dd)*DN+n], a);
        ((float*)(smb+INO))[t] = a;
    }

    int k81 = t >> 5, sq1 = t & 31;
    int gs1 = blk*32 + sq1;
    size_t cb1 = (size_t)(gs1 & 255)*DD*414 + (gs1>>8)*18 + k81;   // hsel=0
    int d1 = t*16;

    const int mt0 = 2*w;
    const int jt  = mt0>>2, r3 = mt0&3;
    const int j8  = jt*2 + (lhi>>1);
    const int sub = (lhi&1)*8 + r3*2;
    const int j0  = jt*16 + lhi*4 + r3;

    __syncthreads();

    if (t < 288){
        uint4 a0 = ntload4(zlin + cb1);
        *(uint4*)(smb + XB0O + d1) = a0;
    }
    __syncthreads();

    for (int step = 0; step < DD + DY; ++step){
        const int ps  = step & 1;
        const int xb  = ps ? XB1O : XB0O;
        const int xbn = ps ? XB0O : XB1O;
        const bool do_stage = (step + 1 < DD);
        const char* h0rd = smb + U1H0 + (ps^1)*9728;
        char*       h0wr = smb + U1H0 + ps*9728;
        const char* h1rd = smb + U1H1 + (ps^1)*8192;
        char*       h1wr = smb + U1H1 + ps*8192;

        v8bf P0, P1;   // L1 kt=0 weight prefetch (issued pre-barrier)

        // ---------------- L0 MFMA (+ stage x(step+1)) ----------------
        {
            uint4 sv0; sv0.x=sv0.y=sv0.z=sv0.w=0u;
            if (do_stage && t < 288)
                sv0 = ntload4(zlin + (size_t)(step+1)*414 + cb1);

            f32x4 acc[2][2];
            #pragma unroll
            for (int mi=0;mi<2;mi++){
                f32x4 bv = *(const f32x4*)(smb + B0O + (j0+mi)*16);
                acc[mi][0] = bv; acc[mi][1] = bv;
            }
            #pragma unroll 2
            for (int kt=0; kt<7; ++kt){
                const v8bf* wrow = w0p + (size_t)(kt*32 + mt0)*64 + l;
                v8bf A0 = wrow[0], A1 = wrow[64];
                int k8 = kt*4 + lhi;
                bool inx = (k8 <= 8);
                const char* hib = inx ? (smb + xb + k8*512) : (h0rd + (k8-9)*512);
                v8bf BH0 = *(const v8bf*)(hib + llo*16);
                v8bf BH1 = *(const v8bf*)(hib + 256 + llo*16);
                MFMA_(acc[0][0], A0, BH0);
                MFMA_(acc[1][0], A1, BH0);
                MFMA_(acc[0][1], A0, BH1);
                MFMA_(acc[1][1], A1, BH1);
            }

            // prefetch L1 kt=0 A-frags (global; overlaps ACT + barrier wait)
            {
                const v8bf* w1r0 = w1p + (size_t)mt0*64 + l;
                P0 = w1r0[0]; P1 = w1r0[64];
            }

            if (do_stage && t < 288)
                *(uint4*)(smb + xbn + d1) = sv0;

            if (step < DD && t < 288){
                const unsigned short* hp = (const unsigned short*)(smb + xb + t*16);
                float* xs = (float*)(smb + X2O);
                #pragma unroll
                for (int e=0;e<8;e++) xs[e*288+t] += bf2f(hp[e]);
            }

            // ACT L0 (raw exp2/rcp)
            {
                f32x4 c0v = *(const f32x4*)(smb + C0O + t*16);
                #pragma unroll
                for (int nt=0;nt<2;nt++){
                    float hf[2];
                    #pragma unroll
                    for (int mi=0;mi<2;mi++){
                        f32x4 a = acc[mi][nt];
                        float ii = fsig2(a[0]), ff = fsig2(a[1]), gg = ftanh2(a[2]), oo = fsig2(a[3]);
                        float c = ff*c0v[mi*2+nt] + ii*gg;
                        c0v[mi*2+nt] = c;
                        hf[mi] = oo*ftanhc(c);
                    }
                    unsigned ph = pkbf(hf[0], hf[1]);
                    int bo = j8*512 + (nt*16+llo)*16 + sub;
                    *(unsigned*)(h0wr + bo) = ph;
                }
                *(f32x4*)(smb + C0O + t*16) = c0v;
            }
            __syncthreads();   // THE barrier
        }

        // ---------------- L1 MFMA (kt=0 peeled, weights prefetched) ----------
        {
            f32x4 acc1[2][2];
            #pragma unroll
            for (int mi=0;mi<2;mi++){
                f32x4 bv = *(const f32x4*)(smb + B1O + (j0+mi)*16);
                acc1[mi][0] = bv; acc1[mi][1] = bv;
            }
            {   // kt = 0: k8 = lhi < 16 -> h0wr
                const char* hib = h0wr + lhi*512;
                v8bf BH0 = *(const v8bf*)(hib + llo*16);
                v8bf BH1 = *(const v8bf*)(hib + 256 + llo*16);
                MFMA_(acc1[0][0], P0, BH0);
                MFMA_(acc1[1][0], P1, BH0);
                MFMA_(acc1[0][1], P0, BH1);
                MFMA_(acc1[1][1], P1, BH1);
            }
            #pragma unroll 2
            for (int kt=1; kt<8; ++kt){
                const v8bf* wrow = w1p + (size_t)(kt*32 + mt0)*64 + l;
                v8bf A0 = wrow[0], A1 = wrow[64];
                int k8 = kt*4 + lhi;
                const char* hib = (k8 < 16) ? (h0wr + k8*512) : (h1rd + (k8-16)*512);
                v8bf BH0 = *(const v8bf*)(hib + llo*16);
                v8bf BH1 = *(const v8bf*)(hib + 256 + llo*16);
                MFMA_(acc1[0][0], A0, BH0);
                MFMA_(acc1[1][0], A1, BH0);
                MFMA_(acc1[0][1], A0, BH1);
                MFMA_(acc1[1][1], A1, BH1);
            }

            // ACT L1 (raw exp2/rcp)
            {
                f32x4 c1v = *(const f32x4*)(smb + C1O + t*16);
                #pragma unroll
                for (int nt=0;nt<2;nt++){
                    float hf[2];
                    #pragma unroll
                    for (int mi=0;mi<2;mi++){
                        f32x4 a = acc1[mi][nt];
                        float ii = fsig2(a[0]), ff = fsig2(a[1]), gg = ftanh2(a[2]), oo = fsig2(a[3]);
                        float c = ff*c1v[mi*2+nt] + ii*gg;
                        c1v[mi*2+nt] = c;
                        hf[mi] = oo*ftanhc(c);
                    }
                    unsigned ph = pkbf(hf[0], hf[1]);
                    int bo = j8*512 + (nt*16+llo)*16 + sub;
                    *(unsigned*)(h1wr + bo) = ph;
                }
                *(f32x4*)(smb + C1O + t*16) = c1v;
            }
        }

        // ---- step 27: build decoder mean input into BOTH XB buffers
        if (step == DD-1){
            __syncthreads();
            if (t < 288){
                const float* xs = (const float*)(smb + X2O);
                __align__(16) unsigned short hb8[8];
                #pragma unroll
                for (int e=0;e<8;e++) hb8[e] = f2bf(xs[e*288+t] * (1.f/(float)DD));
                *(uint4*)(smb + XB0O + t*16) = *(const uint4*)hb8;
                *(uint4*)(smb + XB1O + t*16) = *(const uint4*)hb8;
            }
            __syncthreads();
        }

        // ---- decoder FC
        if (step >= DD){
            __syncthreads();
            if (t < 256){
                int seq = t>>3, l8 = t&7;
                const unsigned short* uh = (const unsigned short*)(smb + U1H1 + ps*8192);
                const float* fw = (const float*)(smb+FCO);
                float a = 0.f;
                #pragma unroll
                for (int half=0; half<2; ++half){
                    int k8 = l8*2 + half;
                    int base = (k8*32 + seq)*8;
                    #pragma unroll
                    for (int e=0;e<8;e++){
                        int j = l8*16 + half*8 + e;
                        a = fmaf(fw[j], bf2f(uh[base+e]), a);
                    }
                }
                a += __shfl_down(a, 4, 8);
                a += __shfl_down(a, 2, 8);
                a += __shfl_down(a, 1, 8);
                if (l8 == 0){
                    int gseq = blk*32 + seq, n = gseq>>8, bb = gseq&255;
                    float yv = fmaxf(a + ((const float*)(smb+INO))[seq] + fw[128], 0.f);
                    __builtin_nontemporal_store(yv, &outy[((size_t)bb*DY + (step-DD))*DN + n]);
                }
            }
        }
    }
}

// ---------------------------------------------------------------------------
extern "C" void kernel_launch(void* const* d_in, const int* in_sizes, int n_in,
                              void* d_out, int out_size, void* d_ws, size_t ws_size,
                              hipStream_t stream)
{
    const float* x         = (const float*)d_in[0];
    const float* adj_real  = (const float*)d_in[1];
    const float* infection = (const float*)d_in[2];
    const int*   day_order = (const int*)  d_in[3];
    const float* gl_w1     = (const float*)d_in[4];
    const float* gl_b1     = (const float*)d_in[5];
    const float* gl_w2     = (const float*)d_in[6];
    const float* gl_b2     = (const float*)d_in[7];
    const float* glp       = (const float*)d_in[8];
    const float* gcn_w     = (const float*)d_in[9];
    const float* vvec      = (const float*)d_in[10];
    const float* wih0      = (const float*)d_in[11];
    const float* whh0      = (const float*)d_in[12];
    const float* b0        = (const float*)d_in[13];
    const float* wih1      = (const float*)d_in[14];
    const float* whh1      = (const float*)d_in[15];
    const float* b1        = (const float*)d_in[16];
    const float* fcw       = (const float*)d_in[17];
    const float* fcb       = (const float*)d_in[18];

    uint8_t* wsb = (uint8_t*)d_ws;
    uint4*          zlin = (uint4*)(wsb);
    unsigned short* wb0  = (unsigned short*)(wsb + WB0_OFF);
    unsigned short* wb1  = (unsigned short*)(wsb + WB1_OFF);
    unsigned short* wpk  = (unsigned short*)(wsb + WPK_OFF);
    unsigned short* gpk  = (unsigned short*)(wsb + GPK_OFF);
    float* out_adj = (float*)d_out;
    float* out_y   = out_adj + ADJSZ;

    kernPrep<<<dim3(1248), dim3(256), 0, stream>>>(wih0, whh0, wih1, whh1,
                                                   gl_w1, gl_w2, gcn_w,
                                                   wb0, wb1, wpk, gpk);
    kernA<<<dim3(DB*DD), dim3(256), 0, stream>>>(x, adj_real, infection, day_order,
                                                 gl_b1, gl_b2, glp, vvec,
                                                 (const v8bf*)wpk, (const v8bf*)gpk,
                                                 out_adj, zlin);
    kernB<<<dim3(GBLK), dim3(1024), 0, stream>>>(zlin, (const v8bf*)wb0,
                                                 (const v8bf*)wb1, b0, b1, infection,
                                                 fcw, fcb, out_y);
}